// Round 16
// baseline (1061.768 us; speedup 1.0000x reference)
//
#include <hip/hip_runtime.h>
#include <hip/hip_bf16.h>
#include <stdint.h>

// Problem constants
#define B_  4
#define S_  2048
#define D_  2048
#define H_  16
#define DH_ 128
#define FF_ 8192

typedef __bf16 bf16x8 __attribute__((ext_vector_type(8)));
typedef __bf16 bf16x4 __attribute__((ext_vector_type(4)));
typedef __bf16 bf16x2 __attribute__((ext_vector_type(2)));
typedef float  f32x4  __attribute__((ext_vector_type(4)));

__device__ __forceinline__ void gll16(const void* g, void* l) {
    __builtin_amdgcn_global_load_lds(
        (const __attribute__((address_space(1))) void*)(g),
        (__attribute__((address_space(3))) void*)(l), 16, 0, 0);
}

// ---------------------------------------------------------------------------
// fp32 -> bf16 elementwise conversion
// ---------------------------------------------------------------------------
__global__ void f2b_kernel(const float* __restrict__ in, __bf16* __restrict__ out, int n)
{
    int i = blockIdx.x * blockDim.x + threadIdx.x;
    int stride = gridDim.x * blockDim.x;
    for (int j = i; j * 4 < n; j += stride) {
        float4 v = *(const float4*)(in + (size_t)j * 4);
        bf16x4 o = {(__bf16)v.x, (__bf16)v.y, (__bf16)v.z, (__bf16)v.w};
        *(bf16x4*)(out + (size_t)j * 4) = o;
    }
}

// ---------------------------------------------------------------------------
// GEMM v5: m201-faithful 8-phase schedule. 256x256, BK=64, 512 thr (8 waves).
// Each phase = {BAR; lgkmcnt(0); sched_barrier; setprio; 16 PURE MFMA;
// setprio; [counted vmcnt]; BAR}; ALL ds_reads + global_load_lds staging live
// in the inter-bracket regions, feeding the NEXT phase's MFMA -> read bursts
// overlap laggard waves' MFMA bursts (DS/MFMA pipe overlap).
// Race-free: every read completes (own lgkmcnt(0)) before the bracket's
// closing barrier; every overwriting STQ issues after that barrier.
// vmcnt: P3 newest-6 = t+2's R0-R2 -> t+1 landed; P7 newest-8 = t+3's -> t+2.
// EPI: 0 = bias ; 1 = bias+relu ; 2 = bias, write transposed Vt[b][h][dh][s]
// ---------------------------------------------------------------------------
template<int EPI>
__global__ __launch_bounds__(512, 1)
void gemm8p(const __bf16* __restrict__ A, const __bf16* __restrict__ Bw,
            const float* __restrict__ bias, __bf16* __restrict__ Cout,
            int M, int N, int K)
{
    __shared__ __align__(16) __bf16 S[65536];   // 128 KiB: A0|A1|B0|B1

    const int tid  = threadIdx.x;
    const int lane = tid & 63;
    const int wid  = tid >> 6;
    const int wr   = wid >> 2;
    const int wc   = wid & 3;
    const int fr   = lane & 15;
    const int fq   = lane >> 4;

    const int gx  = gridDim.x;
    const int nwg = gx * gridDim.y;
    int bid = blockIdx.y * gx + blockIdx.x;
    bid = (bid & 7) * (nwg >> 3) + (bid >> 3);
    const int m0 = (bid / gx) << 8;
    const int n0 = (bid % gx) << 8;

    f32x4 zero = {0.f, 0.f, 0.f, 0.f};
    f32x4 acc[8][4];
#pragma unroll
    for (int m = 0; m < 8; ++m)
#pragma unroll
        for (int n = 0; n < 4; ++n) acc[m][n] = zero;

    const int srow8 = tid >> 3;
    const int sxo   = (((tid & 7) ^ (srow8 & 7)) << 3);
    const size_t Ksz = (size_t)K;
    const __bf16* gA = A  + (size_t)m0 * Ksz;
    const __bf16* gB = Bw + (size_t)n0 * Ksz;

    const int acol0 = ((fq)     ^ (fr & 7)) << 3;
    const int acol1 = ((4 + fq) ^ (fr & 7)) << 3;

    const int NT = K >> 6;
    const int NI = NT >> 1;

#define STQ(gp, tt, q, lofs)                                                  \
    gll16((gp) + (size_t)((q) * 64 + srow8) * Ksz + (size_t)(tt) * 64 + sxo,  \
          &S[(lofs) + (q) * 4096 + tid * 8])

#define RDA(buf, mh)                                                          \
    _Pragma("unroll")                                                         \
    for (int mi = 0; mi < 4; ++mi) {                                          \
        af[mi][0] = *(const bf16x8*)&S[(buf) * 16384 +                        \
                        (wr * 128 + (mh) * 64 + mi * 16 + fr) * 64 + acol0];  \
        af[mi][1] = *(const bf16x8*)&S[(buf) * 16384 +                        \
                        (wr * 128 + (mh) * 64 + mi * 16 + fr) * 64 + acol1];  \
    }

#define RDB1(buf, n_)                                                         \
    bf[n_][0] = *(const bf16x8*)&S[32768 + (buf) * 16384 +                    \
                    (wc * 64 + (n_) * 16 + fr) * 64 + acol0];                 \
    bf[n_][1] = *(const bf16x8*)&S[32768 + (buf) * 16384 +                    \
                    (wc * 64 + (n_) * 16 + fr) * 64 + acol1];

#define MM(mh, na, nb)                                                        \
    __builtin_amdgcn_s_setprio(1);                                            \
    _Pragma("unroll")                                                         \
    for (int mi = 0; mi < 4; ++mi) {                                          \
        acc[(mh)*4+mi][na] = __builtin_amdgcn_mfma_f32_16x16x32_bf16(         \
            af[mi][0], bf[na][0], acc[(mh)*4+mi][na], 0, 0, 0);               \
        acc[(mh)*4+mi][na] = __builtin_amdgcn_mfma_f32_16x16x32_bf16(         \
            af[mi][1], bf[na][1], acc[(mh)*4+mi][na], 0, 0, 0);               \
        acc[(mh)*4+mi][nb] = __builtin_amdgcn_mfma_f32_16x16x32_bf16(         \
            af[mi][0], bf[nb][0], acc[(mh)*4+mi][nb], 0, 0, 0);               \
        acc[(mh)*4+mi][nb] = __builtin_amdgcn_mfma_f32_16x16x32_bf16(         \
            af[mi][1], bf[nb][1], acc[(mh)*4+mi][nb], 0, 0, 0);               \
    }                                                                         \
    __builtin_amdgcn_s_setprio(0);

#define FENCE asm volatile("" ::: "memory")
#define BAR   FENCE; __builtin_amdgcn_s_barrier(); FENCE
#define LGKM0 asm volatile("s_waitcnt lgkmcnt(0)" ::: "memory");              \
              __builtin_amdgcn_sched_barrier(0)

    // prologue: stage tiles 0,1; publish tile 0; pre-issue P0's reads
#pragma unroll
    for (int q = 0; q < 4; ++q) { STQ(gA, 0, q, 0);     STQ(gB, 0, q, 32768); }
#pragma unroll
    for (int q = 0; q < 4; ++q) { STQ(gA, 1, q, 16384); STQ(gB, 1, q, 49152); }
    asm volatile("s_waitcnt vmcnt(8)" ::: "memory");   // tile 0 landed
    BAR;

    bf16x8 af[4][2], bf[4][2];
    RDA(0, 0); RDB1(0, 0); RDB1(0, 1);                 // reads for P0

    for (int i = 0; i < NI; ++i) {
        const int t = 2 * i;
        const bool g = (t + 2) < NT;

        // ---- P0: MFMA buf0 mh0 x n{0,1} ----
        BAR; LGKM0;
        MM(0, 0, 1);
        BAR;
        RDB1(0, 2); RDB1(0, 3);                        // for P1
        if (g) { STQ(gA, t + 2, 0, 0); STQ(gA, t + 2, 2, 0); }
        // ---- P1 ----
        BAR; LGKM0;
        MM(0, 2, 3);
        BAR;
        RDA(0, 1);                                     // for P2
        if (g) { STQ(gB, t + 2, 0, 32768); STQ(gB, t + 2, 1, 32768); }
        // ---- P2 ----
        BAR; LGKM0;
        MM(1, 0, 1);
        BAR;
        if (g) { STQ(gB, t + 2, 2, 32768); STQ(gB, t + 2, 3, 32768); }
        // ---- P3 ----
        BAR; LGKM0;
        MM(1, 2, 3);
        if (g) asm volatile("s_waitcnt vmcnt(6)" ::: "memory"); // t+1 landed
        else   asm volatile("s_waitcnt vmcnt(0)" ::: "memory");
        BAR;
        RDA(1, 0); RDB1(1, 0); RDB1(1, 1);             // for P4 (buf1)
        if (g) { STQ(gA, t + 2, 1, 0); STQ(gA, t + 2, 3, 0); }
        // ---- P4 ----
        BAR; LGKM0;
        MM(0, 0, 1);
        BAR;
        RDB1(1, 2); RDB1(1, 3);                        // for P5
        if (g) { STQ(gA, t + 3, 0, 16384); STQ(gA, t + 3, 2, 16384); }
        // ---- P5 ----
        BAR; LGKM0;
        MM(0, 2, 3);
        BAR;
        RDA(1, 1);                                     // for P6
        if (g) { STQ(gB, t + 3, 0, 49152); STQ(gB, t + 3, 1, 49152); }
        // ---- P6 ----
        BAR; LGKM0;
        MM(1, 0, 1);
        BAR;
        if (g) { STQ(gB, t + 3, 2, 49152); STQ(gB, t + 3, 3, 49152);
                 STQ(gA, t + 3, 1, 16384); STQ(gA, t + 3, 3, 16384); }
        // ---- P7 ----
        BAR; LGKM0;
        MM(1, 2, 3);
        if (g) asm volatile("s_waitcnt vmcnt(8)" ::: "memory"); // t+2 landed
        else   asm volatile("s_waitcnt vmcnt(0)" ::: "memory");
        BAR;
        RDA(0, 0); RDB1(0, 0); RDB1(0, 1);             // for next iter's P0
    }
#undef STQ
#undef RDA
#undef RDB1
#undef MM
#undef FENCE
#undef BAR
#undef LGKM0

#pragma unroll
    for (int am = 0; am < 8; ++am) {
#pragma unroll
        for (int n = 0; n < 4; ++n) {
            const int col = n0 + wc * 64 + n * 16 + fr;
            const float bv = bias[col];
            if (EPI == 2) {
                const int row0 = m0 + wr * 128 + am * 16 + fq * 4;
                const int bi = row0 >> 11;
                const int si = row0 & (S_ - 1);
                bf16x4 o4;
#pragma unroll
                for (int r = 0; r < 4; ++r) o4[r] = (__bf16)(acc[am][n][r] + bv);
                *(bf16x4*)&Cout[(((size_t)bi * H_ + (col >> 7)) * DH_ + (col & (DH_ - 1))) * S_ + si] = o4;
            } else {
#pragma unroll
                for (int r = 0; r < 4; ++r) {
                    const int row = m0 + wr * 128 + am * 16 + fq * 4 + r;
                    float v = acc[am][n][r] + bv;
                    if (EPI == 1) v = fmaxf(v, 0.f);
                    Cout[(size_t)row * N + col] = (__bf16)v;
                }
            }
        }
    }
}

// ---------------------------------------------------------------------------
// Per-head LayerNorm over DH=128 (qk-norm), in-place on bf16, scale folded.
// ---------------------------------------------------------------------------
__global__ __launch_bounds__(256)
void qk_norm_ip(__bf16* __restrict__ data, float scale)
{
    const int row = blockIdx.x * 4 + (threadIdx.x >> 6);
    const int t   = threadIdx.x & 63;
    const size_t base = (size_t)row * DH_;
    bf16x2 v2 = *(bf16x2*)(data + base + t * 2);
    const float a = (float)v2[0], b = (float)v2[1];
    float s  = a + b;
    float s2 = a * a + b * b;
#pragma unroll
    for (int o = 32; o; o >>= 1) { s += __shfl_xor(s, o); s2 += __shfl_xor(s2, o); }
    const float mean = s * (1.f / DH_);
    const float var  = s2 * (1.f / DH_) - mean * mean;
    const float rstd = rsqrtf(var + 1e-5f) * scale;
    bf16x2 o2 = {(__bf16)((a - mean) * rstd), (__bf16)((b - mean) * rstd)};
    *(bf16x2*)(data + base + t * 2) = o2;
}

// ---------------------------------------------------------------------------
// add_ln_x: x (fp32) + a (bf16) -> LN -> bf16 out.
// ---------------------------------------------------------------------------
__global__ __launch_bounds__(256)
void add_ln_x(const float* __restrict__ X, const __bf16* __restrict__ A2,
              __bf16* __restrict__ outb)
{
    __shared__ float ls[4], ls2[4];
    const int row = blockIdx.x;
    const int t   = threadIdx.x;
    const size_t base = (size_t)row * D_;

    float4 a = *(const float4*)(X + base + t * 8);
    float4 b = *(const float4*)(X + base + t * 8 + 4);
    bf16x8 c8 = *(const bf16x8*)(A2 + base + t * 8);
    float v[8] = {a.x + (float)c8[0], a.y + (float)c8[1], a.z + (float)c8[2], a.w + (float)c8[3],
                  b.x + (float)c8[4], b.y + (float)c8[5], b.z + (float)c8[6], b.w + (float)c8[7]};
    float s = 0.f, s2 = 0.f;
#pragma unroll
    for (int i = 0; i < 8; ++i) { s += v[i]; s2 += v[i] * v[i]; }
#pragma unroll
    for (int o = 32; o; o >>= 1) { s += __shfl_xor(s, o); s2 += __shfl_xor(s2, o); }
    const int w = t >> 6;
    if ((t & 63) == 0) { ls[w] = s; ls2[w] = s2; }
    __syncthreads();
    s  = ls[0] + ls[1] + ls[2] + ls[3];
    s2 = ls2[0] + ls2[1] + ls2[2] + ls2[3];
    const float mean = s * (1.f / D_);
    const float var  = s2 * (1.f / D_) - mean * mean;
    const float rstd = rsqrtf(var + 1e-5f);

    bf16x8 ob;
#pragma unroll
    for (int i = 0; i < 8; ++i) ob[i] = (__bf16)((v[i] - mean) * rstd);
    *(bf16x8*)(outb + base + t * 8) = ob;
}

// ---------------------------------------------------------------------------
// add_ln_f: x1 (bf16) + f2 (bf16) -> LN -> fp32 out.
// ---------------------------------------------------------------------------
__global__ __launch_bounds__(256)
void add_ln_f(const __bf16* __restrict__ X, const __bf16* __restrict__ A2,
              float* __restrict__ outf)
{
    __shared__ float ls[4], ls2[4];
    const int row = blockIdx.x;
    const int t   = threadIdx.x;
    const size_t base = (size_t)row * D_;

    bf16x8 a8 = *(const bf16x8*)(X  + base + t * 8);
    bf16x8 c8 = *(const bf16x8*)(A2 + base + t * 8);
    float v[8];
#pragma unroll
    for (int i = 0; i < 8; ++i) v[i] = (float)a8[i] + (float)c8[i];
    float s = 0.f, s2 = 0.f;
#pragma unroll
    for (int i = 0; i < 8; ++i) { s += v[i]; s2 += v[i] * v[i]; }
#pragma unroll
    for (int o = 32; o; o >>= 1) { s += __shfl_xor(s, o); s2 += __shfl_xor(s2, o); }
    const int w = t >> 6;
    if ((t & 63) == 0) { ls[w] = s; ls2[w] = s2; }
    __syncthreads();
    s  = ls[0] + ls[1] + ls[2] + ls[3];
    s2 = ls2[0] + ls2[1] + ls2[2] + ls2[3];
    const float mean = s * (1.f / D_);
    const float var  = s2 * (1.f / D_) - mean * mean;
    const float rstd = rsqrtf(var + 1e-5f);

    float4 o0 = {(v[0] - mean) * rstd, (v[1] - mean) * rstd,
                 (v[2] - mean) * rstd, (v[3] - mean) * rstd};
    float4 o1 = {(v[4] - mean) * rstd, (v[5] - mean) * rstd,
                 (v[6] - mean) * rstd, (v[7] - mean) * rstd};
    *(float4*)(outf + base + t * 8)     = o0;
    *(float4*)(outf + base + t * 8 + 4) = o1;
}

// ---------------------------------------------------------------------------
// Flash attention v12 (causal). KVBLK=32, fixed-C softmax, ones-MFMA denom,
// K/V LDS double-buffered one tile ahead, single raw s_barrier per tile,
// TWO m-tiles per wave (QBLK=32/wave, 128 q-rows/block). LDS 42 KiB.
// ---------------------------------------------------------------------------
__global__ __launch_bounds__(256, 2)
void attn_fwd12(const __bf16* __restrict__ Q, const __bf16* __restrict__ K,
                const __bf16* __restrict__ Vt, __bf16* __restrict__ O)
{
    __shared__ __align__(16) __bf16 Ks[2][32 * 128];   // 16 KiB, byte-swizzled
    __shared__ __align__(16) __bf16 Vs[2][128 * 32];   // 16 KiB, byte-swizzled
    __shared__ __align__(16) __bf16 Pl[4][32 * 40];    // 10 KiB, padded rows

    const float CMAX = 11.5f;   // score bound from qk-norm (Cauchy-Schwarz)

    const int tid  = threadIdx.x;
    const int lane = tid & 63;
    const int w    = tid >> 6;
    const int qt   = (int)gridDim.x - 1 - (int)blockIdx.x;  // heavy first
    const int h = blockIdx.y, b = blockIdx.z;
    const int q0w = qt * 128 + w * 32;
    const int fr = lane & 15, fq = lane >> 4;
    const size_t hb  = ((size_t)b * S_) * D_ + (size_t)h * DH_;   // Q,K,O [t][c]
    const size_t vtb = (((size_t)b * H_ + h) * DH_) * S_;          // Vt [dh][s]

    bf16x8 qf[2][4];
#pragma unroll
    for (int m = 0; m < 2; ++m)
#pragma unroll
        for (int ds = 0; ds < 4; ++ds)
            qf[m][ds] = *(const bf16x8*)(Q + hb + (size_t)(q0w + m * 16 + fr) * D_ + ds * 32 + fq * 8);

    f32x4 zero = {0.f, 0.f, 0.f, 0.f};
    f32x4 cacc[2][9];                   // [m][0..7] = ctx, [m][8] = denom
#pragma unroll
    for (int m = 0; m < 2; ++m)
#pragma unroll
        for (int dt = 0; dt < 9; ++dt) cacc[m][dt] = zero;

    bf16x8 ones8;
#pragma unroll
    for (int j = 0; j < 8; ++j) ones8[j] = (__bf16)1.0f;

    int krw[2], kco[2];
#pragma unroll
    for (int p = 0; p < 2; ++p) {
        const int c = p * 256 + tid;
        krw[p] = c >> 4;
        kco[p] = ((((c & 15) * 16) ^ ((krw[p] & 7) << 4)) >> 1);
    }
    int vdh[2], vco[2];
#pragma unroll
    for (int p = 0; p < 2; ++p) {
        const int c = p * 256 + tid;
        vdh[p] = c >> 2;
        vco[p] = (((c & 3) ^ ((vdh[p] ^ (vdh[p] >> 2)) & 3)) << 3);
    }

    int koff[4];
#pragma unroll
    for (int ds = 0; ds < 4; ++ds)
        koff[ds] = (((ds * 64 + fq * 16) ^ ((fr & 7) << 4)) >> 1);

    const int vrg = ((fq ^ ((fr ^ (fr >> 2)) & 3)) << 3);

    const int ntb = 4 * qt + 4;               // block tile count (32-key tiles)
    const int ntw = 4 * qt + w + 1;           // this wave's tiles (wave-uniform)

#define STAGE_KV(t, buf)                                                      \
    {                                                                         \
        const int _t = (t);                                                   \
        _Pragma("unroll")                                                     \
        for (int p = 0; p < 2; ++p)                                           \
            gll16(K + hb + (size_t)(_t * 32 + krw[p]) * D_ + kco[p],          \
                  &Ks[buf][(p * 256 + tid) * 8]);                             \
        _Pragma("unroll")                                                     \
        for (int p = 0; p < 2; ++p)                                           \
            gll16(Vt + vtb + (size_t)vdh[p] * S_ + _t * 32 + vco[p],          \
                  &Vs[buf][(p * 256 + tid) * 8]);                             \
    }

    STAGE_KV(0, 0);

    for (int kt = 0; kt < ntb; ++kt) {
        const int cur = kt & 1;
        asm volatile("s_waitcnt vmcnt(0)" ::: "memory");  // K/V[kt] landed
        __builtin_amdgcn_s_barrier();                     // tile kt-1 readers done
        asm volatile("" ::: "memory");

        if (kt + 1 < ntb) STAGE_KV(kt + 1, cur ^ 1);

        if (kt < ntw) {
            // ---- QK^T: 16 MFMA over 32 keys x 32 q (kfr shared by 2 m) ----
            f32x4 sacc[2][2];
#pragma unroll
            for (int m = 0; m < 2; ++m)
#pragma unroll
                for (int n = 0; n < 2; ++n) sacc[m][n] = zero;
#pragma unroll
            for (int n = 0; n < 2; ++n) {
                const __bf16* krow = &Ks[cur][(n * 16 + fr) * 128];
#pragma unroll
                for (int ds = 0; ds < 4; ++ds) {
                    bf16x8 kfr = *(const bf16x8*)(krow + koff[ds]);
                    sacc[0][n] = __builtin_amdgcn_mfma_f32_16x16x32_bf16(qf[0][ds], kfr, sacc[0][n], 0, 0, 0);
                    sacc[1][n] = __builtin_amdgcn_mfma_f32_16x16x32_bf16(qf[1][ds], kfr, sacc[1][n], 0, 0, 0);
                }
            }

            // ---- fixed-C softmax: p = exp(s - CMAX), mask post-exp ----
#pragma unroll
            for (int m = 0; m < 2; ++m)
#pragma unroll
                for (int r = 0; r < 4; ++r) {
                    const int qi = q0w + m * 16 + fq * 4 + r;
                    const int kb0 = kt * 32 + fr;
                    const float p0 = (kb0      <= qi) ? __expf(sacc[m][0][r] - CMAX) : 0.f;
                    const float p1 = (kb0 + 16 <= qi) ? __expf(sacc[m][1][r] - CMAX) : 0.f;
                    __bf16* pr = &Pl[w][(m * 16 + fq * 4 + r) * 40];
                    pr[fr]      = (__bf16)p0;
                    pr[16 + fr] = (__bf16)p1;
                }

            // ---- PV: 16 MFMA + 2 denom MFMA (vf shared by 2 m) ----
            bf16x8 pf0 = *(const bf16x8*)&Pl[w][(fr) * 40 + fq * 8];
            bf16x8 pf1 = *(const bf16x8*)&Pl[w][(16 + fr) * 40 + fq * 8];
            const __bf16* vbase = &Vs[cur][0];
#pragma unroll
            for (int dt = 0; dt < 8; ++dt) {
                bf16x8 vf = *(const bf16x8*)&vbase[(dt * 16 + fr) * 32 + vrg];
                cacc[0][dt] = __builtin_amdgcn_mfma_f32_16x16x32_bf16(pf0, vf, cacc[0][dt], 0, 0, 0);
                cacc[1][dt] = __builtin_amdgcn_mfma_f32_16x16x32_bf16(pf1, vf, cacc[1][dt], 0, 0, 0);
            }
            cacc[0][8] = __builtin_amdgcn_mfma_f32_16x16x32_bf16(pf0, ones8, cacc[0][8], 0, 0, 0);
            cacc[1][8] = __builtin_amdgcn_mfma_f32_16x16x32_bf16(pf1, ones8, cacc[1][8], 0, 0, 0);
        }
    }
#undef STAGE_KV

    // epilogue: normalize by MFMA-computed denominator + store
#pragma unroll
    for (int m = 0; m < 2; ++m)
#pragma unroll
        for (int dt = 0; dt < 8; ++dt)
#pragma unroll
            for (int r = 0; r < 4; ++r) {
                const int qi = q0w + m * 16 + fq * 4 + r;
                O[hb + (size_t)qi * D_ + dt * 16 + fr] = (__bf16)(cacc[m][dt][r] / cacc[m][8][r]);
            }
}

// ---------------------------------------------------------------------------
// launch — total workspace use: exactly 256 MiB
// ---------------------------------------------------------------------------
extern "C" void kernel_launch(void* const* d_in, const int* in_sizes, int n_in,
                              void* d_out, int out_size, void* d_ws, size_t ws_size,
                              hipStream_t stream)
{
    const float* x  = (const float*)d_in[0];
    const float* Wq = (const float*)d_in[2];  const float* bq = (const float*)d_in[3];
    const float* Wk = (const float*)d_in[4];  const float* bk = (const float*)d_in[5];
    const float* Wv = (const float*)d_in[6];  const float* bv = (const float*)d_in[7];
    const float* Wo = (const float*)d_in[8];  const float* bo = (const float*)d_in[9];
    const float* W1 = (const float*)d_in[10]; const float* b1 = (const float*)d_in[11];
    const float* W2 = (const float*)d_in[12]; const float* b2 = (const float*)d_in[13];
    float* out = (float*)d_out;

    const size_t NT  = (size_t)B_ * S_;            // 8192 rows
    const size_t MB  = 1024 * 1024;
    const size_t NEED = 256 * MB;
    if (ws_size < NEED) return;

    uint8_t* ws = (uint8_t*)d_ws;
    __bf16* Wb   = (__bf16*)(ws);              // 32 MiB: weight staging (reused 6x)
    __bf16* xb   = (__bf16*)(ws + 32  * MB);   // 32 MiB: x bf16; later x1b
    __bf16* vtt  = (__bf16*)(ws + 64  * MB);   // 32 MiB: V transposed [b][h][dh][s]
    __bf16* fb   = (__bf16*)(ws + 96  * MB);   // 32 MiB: attn_out bf16; later f2 bf16
    __bf16* h1   = (__bf16*)(ws + 128 * MB);   // 128 MiB: FF hidden; hosts K/Q/ctx early
    __bf16* kb   = h1;
    __bf16* qb   = h1 + 16 * MB;
    __bf16* ctxb = h1 + 32 * MB;
    __bf16* x1b  = xb;

    const dim3 blk2(512);
    const dim3 gD(D_ / 256, NT / 256);     // (8, 32)   = 256 blocks
    const dim3 gF(FF_ / 256, NT / 256);    // (32, 32)  = 1024 blocks

    f2b_kernel<<<2048, 256, 0, stream>>>(x, xb, (int)(NT * D_));

    f2b_kernel<<<1024, 256, 0, stream>>>(Wq, Wb, D_ * D_);
    gemm8p<0><<<gD, blk2, 0, stream>>>(xb, Wb, bq, qb, (int)NT, D_, D_);
    f2b_kernel<<<1024, 256, 0, stream>>>(Wk, Wb, D_ * D_);
    gemm8p<0><<<gD, blk2, 0, stream>>>(xb, Wb, bk, kb, (int)NT, D_, D_);
    f2b_kernel<<<1024, 256, 0, stream>>>(Wv, Wb, D_ * D_);
    gemm8p<2><<<gD, blk2, 0, stream>>>(xb, Wb, bv, vtt, (int)NT, D_, D_);

    qk_norm_ip<<<(int)(NT * H_ / 4), 256, 0, stream>>>(qb, 0.08838834764831845f);
    qk_norm_ip<<<(int)(NT * H_ / 4), 256, 0, stream>>>(kb, 1.0f);

    attn_fwd12<<<dim3(S_ / 128, H_, B_), 256, 0, stream>>>(qb, kb, vtt, ctxb);

    f2b_kernel<<<1024, 256, 0, stream>>>(Wo, Wb, D_ * D_);
    gemm8p<0><<<gD, blk2, 0, stream>>>(ctxb, Wb, bo, fb, (int)NT, D_, D_);
    add_ln_x<<<(int)NT, 256, 0, stream>>>(x, fb, x1b);

    f2b_kernel<<<2048, 256, 0, stream>>>(W1, Wb, FF_ * D_);
    gemm8p<1><<<gF, blk2, 0, stream>>>(x1b, Wb, b1, h1, (int)NT, FF_, D_);
    f2b_kernel<<<2048, 256, 0, stream>>>(W2, Wb, D_ * FF_);
    gemm8p<0><<<gD, blk2, 0, stream>>>(h1, Wb, b2, fb, (int)NT, D_, FF_);

    add_ln_f<<<(int)NT, 256, 0, stream>>>(x1b, fb, out);
}

// Round 17
// 1028.905 us; speedup vs baseline: 1.0319x; 1.0319x over previous
//
#include <hip/hip_runtime.h>
#include <hip/hip_bf16.h>
#include <stdint.h>

// Problem constants
#define B_  4
#define S_  2048
#define D_  2048
#define H_  16
#define DH_ 128
#define FF_ 8192

typedef __bf16 bf16x8 __attribute__((ext_vector_type(8)));
typedef __bf16 bf16x4 __attribute__((ext_vector_type(4)));
typedef __bf16 bf16x2 __attribute__((ext_vector_type(2)));
typedef float  f32x4  __attribute__((ext_vector_type(4)));

__device__ __forceinline__ void gll16(const void* g, void* l) {
    __builtin_amdgcn_global_load_lds(
        (const __attribute__((address_space(1))) void*)(g),
        (__attribute__((address_space(3))) void*)(l), 16, 0, 0);
}

// ---------------------------------------------------------------------------
// fp32 -> bf16 elementwise conversion
// ---------------------------------------------------------------------------
__global__ void f2b_kernel(const float* __restrict__ in, __bf16* __restrict__ out, int n)
{
    int i = blockIdx.x * blockDim.x + threadIdx.x;
    int stride = gridDim.x * blockDim.x;
    for (int j = i; j * 4 < n; j += stride) {
        float4 v = *(const float4*)(in + (size_t)j * 4);
        bf16x4 o = {(__bf16)v.x, (__bf16)v.y, (__bf16)v.z, (__bf16)v.w};
        *(bf16x4*)(out + (size_t)j * 4) = o;
    }
}

// ---------------------------------------------------------------------------
// f2b4: convert four DxD fp32 weights into four contiguous bf16 regions of
// one buffer in a single dispatch (removes 3 launches + serialization).
// ---------------------------------------------------------------------------
__global__ void f2b4_kernel(const float* __restrict__ w0, const float* __restrict__ w1,
                            const float* __restrict__ w2, const float* __restrict__ w3,
                            __bf16* __restrict__ out)
{
    const int n4 = (D_ * D_) >> 2;              // float4s per weight
    int i = blockIdx.x * blockDim.x + threadIdx.x;
    int stride = gridDim.x * blockDim.x;
    for (int j = i; j < 4 * n4; j += stride) {
        const int wsel = j / n4;
        const int loc  = j - wsel * n4;
        const float* src = (wsel == 0) ? w0 : (wsel == 1) ? w1 : (wsel == 2) ? w2 : w3;
        float4 v = *(const float4*)(src + (size_t)loc * 4);
        bf16x4 o = {(__bf16)v.x, (__bf16)v.y, (__bf16)v.z, (__bf16)v.w};
        *(bf16x4*)(out + (size_t)j * 4) = o;
    }
}

// ---------------------------------------------------------------------------
// GEMM v4 (best known): 8-phase deep-pipelined 256x256, BK=64, 512 thr
// (8 waves 2Mx4N). LDS 128 KiB A/B x 2 bufs, full-spread XOR swizzle
// (source pre-swizzled, linear gll16 dest). Quarter-tile staging woven into
// phases; counted vmcnt only (6 @P3, 8 @P7); drains only on last iteration.
// EPI: 0 = bias ; 1 = bias+relu ; 2 = bias, write transposed Vt[b][h][dh][s]
// ---------------------------------------------------------------------------
template<int EPI>
__global__ __launch_bounds__(512, 1)
void gemm8p(const __bf16* __restrict__ A, const __bf16* __restrict__ Bw,
            const float* __restrict__ bias, __bf16* __restrict__ Cout,
            int M, int N, int K)
{
    __shared__ __align__(16) __bf16 S[65536];   // 128 KiB: A0|A1|B0|B1

    const int tid  = threadIdx.x;
    const int lane = tid & 63;
    const int wid  = tid >> 6;
    const int wr   = wid >> 2;
    const int wc   = wid & 3;
    const int fr   = lane & 15;
    const int fq   = lane >> 4;

    const int gx  = gridDim.x;
    const int nwg = gx * gridDim.y;
    int bid = blockIdx.y * gx + blockIdx.x;
    bid = (bid & 7) * (nwg >> 3) + (bid >> 3);
    const int m0 = (bid / gx) << 8;
    const int n0 = (bid % gx) << 8;

    f32x4 zero = {0.f, 0.f, 0.f, 0.f};
    f32x4 acc[8][4];
#pragma unroll
    for (int m = 0; m < 8; ++m)
#pragma unroll
        for (int n = 0; n < 4; ++n) acc[m][n] = zero;

    const int srow8 = tid >> 3;
    const int sxo   = (((tid & 7) ^ (srow8 & 7)) << 3);
    const size_t Ksz = (size_t)K;
    const __bf16* gA = A  + (size_t)m0 * Ksz;
    const __bf16* gB = Bw + (size_t)n0 * Ksz;

    const int acol0 = ((fq)     ^ (fr & 7)) << 3;
    const int acol1 = ((4 + fq) ^ (fr & 7)) << 3;

    const int NT = K >> 6;
    const int NI = NT >> 1;

#define STQ(gp, tt, q, lofs)                                                  \
    gll16((gp) + (size_t)((q) * 64 + srow8) * Ksz + (size_t)(tt) * 64 + sxo,  \
          &S[(lofs) + (q) * 4096 + tid * 8])

#define RDA(buf, mh)                                                          \
    _Pragma("unroll")                                                         \
    for (int mi = 0; mi < 4; ++mi) {                                          \
        af[mi][0] = *(const bf16x8*)&S[(buf) * 16384 +                        \
                        (wr * 128 + (mh) * 64 + mi * 16 + fr) * 64 + acol0];  \
        af[mi][1] = *(const bf16x8*)&S[(buf) * 16384 +                        \
                        (wr * 128 + (mh) * 64 + mi * 16 + fr) * 64 + acol1];  \
    }

#define RDB1(buf, n_)                                                         \
    bf[n_][0] = *(const bf16x8*)&S[32768 + (buf) * 16384 +                    \
                    (wc * 64 + (n_) * 16 + fr) * 64 + acol0];                 \
    bf[n_][1] = *(const bf16x8*)&S[32768 + (buf) * 16384 +                    \
                    (wc * 64 + (n_) * 16 + fr) * 64 + acol1];

#define MM(mh, na, nb)                                                        \
    __builtin_amdgcn_s_setprio(1);                                            \
    _Pragma("unroll")                                                         \
    for (int mi = 0; mi < 4; ++mi) {                                          \
        acc[(mh)*4+mi][na] = __builtin_amdgcn_mfma_f32_16x16x32_bf16(         \
            af[mi][0], bf[na][0], acc[(mh)*4+mi][na], 0, 0, 0);               \
        acc[(mh)*4+mi][na] = __builtin_amdgcn_mfma_f32_16x16x32_bf16(         \
            af[mi][1], bf[na][1], acc[(mh)*4+mi][na], 0, 0, 0);               \
        acc[(mh)*4+mi][nb] = __builtin_amdgcn_mfma_f32_16x16x32_bf16(         \
            af[mi][0], bf[nb][0], acc[(mh)*4+mi][nb], 0, 0, 0);               \
        acc[(mh)*4+mi][nb] = __builtin_amdgcn_mfma_f32_16x16x32_bf16(         \
            af[mi][1], bf[nb][1], acc[(mh)*4+mi][nb], 0, 0, 0);               \
    }                                                                         \
    __builtin_amdgcn_s_setprio(0);

#define FENCE asm volatile("" ::: "memory")
#define BAR   FENCE; __builtin_amdgcn_s_barrier(); FENCE

#pragma unroll
    for (int q = 0; q < 4; ++q) { STQ(gA, 0, q, 0);     STQ(gB, 0, q, 32768); }
#pragma unroll
    for (int q = 0; q < 4; ++q) { STQ(gA, 1, q, 16384); STQ(gB, 1, q, 49152); }
    asm volatile("s_waitcnt vmcnt(8)" ::: "memory");
    BAR;

    for (int i = 0; i < NI; ++i) {
        const int t = 2 * i;
        const bool g = (t + 2) < NT;
        bf16x8 af[4][2], bf[4][2];

        RDA(0, 0); RDB1(0, 0); RDB1(0, 1);
        MM(0, 0, 1);
        RDB1(0, 2); RDB1(0, 3);
        BAR;
        if (g) { STQ(gA, t + 2, 0, 0); STQ(gA, t + 2, 2, 0); }
        MM(0, 2, 3);
        RDA(0, 1);
        BAR;
        if (g) { STQ(gB, t + 2, 0, 32768); STQ(gB, t + 2, 1, 32768); }
        MM(1, 0, 1);
        BAR;
        if (g) { STQ(gB, t + 2, 2, 32768); STQ(gB, t + 2, 3, 32768); }
        MM(1, 2, 3);
        if (g) asm volatile("s_waitcnt vmcnt(6)" ::: "memory");
        else   asm volatile("s_waitcnt vmcnt(0)" ::: "memory");
        BAR;
        RDA(1, 0); RDB1(1, 0); RDB1(1, 1);
        if (g) { STQ(gA, t + 2, 1, 0); STQ(gA, t + 2, 3, 0); }
        MM(0, 0, 1);
        RDB1(1, 2); RDB1(1, 3);
        BAR;
        if (g) { STQ(gA, t + 3, 0, 16384); STQ(gA, t + 3, 2, 16384); }
        MM(0, 2, 3);
        RDA(1, 1);
        BAR;
        if (g) { STQ(gB, t + 3, 0, 49152); STQ(gB, t + 3, 1, 49152); }
        MM(1, 0, 1);
        BAR;
        if (g) { STQ(gB, t + 3, 2, 49152); STQ(gB, t + 3, 3, 49152);
                 STQ(gA, t + 3, 1, 16384); STQ(gA, t + 3, 3, 16384); }
        MM(1, 2, 3);
        if (g) asm volatile("s_waitcnt vmcnt(8)" ::: "memory");
        else   asm volatile("s_waitcnt vmcnt(0)" ::: "memory");
        BAR;
    }
#undef STQ
#undef RDA
#undef RDB1
#undef MM
#undef FENCE
#undef BAR

#pragma unroll
    for (int am = 0; am < 8; ++am) {
#pragma unroll
        for (int n = 0; n < 4; ++n) {
            const int col = n0 + wc * 64 + n * 16 + fr;
            const float bv = bias[col];
            if (EPI == 2) {
                const int row0 = m0 + wr * 128 + am * 16 + fq * 4;
                const int bi = row0 >> 11;
                const int si = row0 & (S_ - 1);
                bf16x4 o4;
#pragma unroll
                for (int r = 0; r < 4; ++r) o4[r] = (__bf16)(acc[am][n][r] + bv);
                *(bf16x4*)&Cout[(((size_t)bi * H_ + (col >> 7)) * DH_ + (col & (DH_ - 1))) * S_ + si] = o4;
            } else {
#pragma unroll
                for (int r = 0; r < 4; ++r) {
                    const int row = m0 + wr * 128 + am * 16 + fq * 4 + r;
                    float v = acc[am][n][r] + bv;
                    if (EPI == 1) v = fmaxf(v, 0.f);
                    Cout[(size_t)row * N + col] = (__bf16)v;
                }
            }
        }
    }
}

// ---------------------------------------------------------------------------
// Fused per-head LayerNorm over DH=128 for Q and K in one dispatch.
// Blocks [0, half) process Q (scale folded), rest process K.
// ---------------------------------------------------------------------------
__global__ __launch_bounds__(256)
void qk_norm2(__bf16* __restrict__ qd, __bf16* __restrict__ kd, int halfBlocks)
{
    const bool isQ = (int)blockIdx.x < halfBlocks;
    __bf16* data = isQ ? qd : kd;
    const float scale = isQ ? 0.08838834764831845f : 1.0f;
    const int bid = isQ ? blockIdx.x : blockIdx.x - halfBlocks;
    const int row = bid * 4 + (threadIdx.x >> 6);
    const int t   = threadIdx.x & 63;
    const size_t base = (size_t)row * DH_;
    bf16x2 v2 = *(bf16x2*)(data + base + t * 2);
    const float a = (float)v2[0], b = (float)v2[1];
    float s  = a + b;
    float s2 = a * a + b * b;
#pragma unroll
    for (int o = 32; o; o >>= 1) { s += __shfl_xor(s, o); s2 += __shfl_xor(s2, o); }
    const float mean = s * (1.f / DH_);
    const float var  = s2 * (1.f / DH_) - mean * mean;
    const float rstd = rsqrtf(var + 1e-5f) * scale;
    bf16x2 o2 = {(__bf16)((a - mean) * rstd), (__bf16)((b - mean) * rstd)};
    *(bf16x2*)(data + base + t * 2) = o2;
}

// ---------------------------------------------------------------------------
// add_ln_x: x (fp32) + a (bf16) -> LN -> bf16 out.
// ---------------------------------------------------------------------------
__global__ __launch_bounds__(256)
void add_ln_x(const float* __restrict__ X, const __bf16* __restrict__ A2,
              __bf16* __restrict__ outb)
{
    __shared__ float ls[4], ls2[4];
    const int row = blockIdx.x;
    const int t   = threadIdx.x;
    const size_t base = (size_t)row * D_;

    float4 a = *(const float4*)(X + base + t * 8);
    float4 b = *(const float4*)(X + base + t * 8 + 4);
    bf16x8 c8 = *(const bf16x8*)(A2 + base + t * 8);
    float v[8] = {a.x + (float)c8[0], a.y + (float)c8[1], a.z + (float)c8[2], a.w + (float)c8[3],
                  b.x + (float)c8[4], b.y + (float)c8[5], b.z + (float)c8[6], b.w + (float)c8[7]};
    float s = 0.f, s2 = 0.f;
#pragma unroll
    for (int i = 0; i < 8; ++i) { s += v[i]; s2 += v[i] * v[i]; }
#pragma unroll
    for (int o = 32; o; o >>= 1) { s += __shfl_xor(s, o); s2 += __shfl_xor(s2, o); }
    const int w = t >> 6;
    if ((t & 63) == 0) { ls[w] = s; ls2[w] = s2; }
    __syncthreads();
    s  = ls[0] + ls[1] + ls[2] + ls[3];
    s2 = ls2[0] + ls2[1] + ls2[2] + ls2[3];
    const float mean = s * (1.f / D_);
    const float var  = s2 * (1.f / D_) - mean * mean;
    const float rstd = rsqrtf(var + 1e-5f);

    bf16x8 ob;
#pragma unroll
    for (int i = 0; i < 8; ++i) ob[i] = (__bf16)((v[i] - mean) * rstd);
    *(bf16x8*)(outb + base + t * 8) = ob;
}

// ---------------------------------------------------------------------------
// add_ln_f: x1 (bf16) + f2 (bf16) -> LN -> fp32 out.
// ---------------------------------------------------------------------------
__global__ __launch_bounds__(256)
void add_ln_f(const __bf16* __restrict__ X, const __bf16* __restrict__ A2,
              float* __restrict__ outf)
{
    __shared__ float ls[4], ls2[4];
    const int row = blockIdx.x;
    const int t   = threadIdx.x;
    const size_t base = (size_t)row * D_;

    bf16x8 a8 = *(const bf16x8*)(X  + base + t * 8);
    bf16x8 c8 = *(const bf16x8*)(A2 + base + t * 8);
    float v[8];
#pragma unroll
    for (int i = 0; i < 8; ++i) v[i] = (float)a8[i] + (float)c8[i];
    float s = 0.f, s2 = 0.f;
#pragma unroll
    for (int i = 0; i < 8; ++i) { s += v[i]; s2 += v[i] * v[i]; }
#pragma unroll
    for (int o = 32; o; o >>= 1) { s += __shfl_xor(s, o); s2 += __shfl_xor(s2, o); }
    const int w = t >> 6;
    if ((t & 63) == 0) { ls[w] = s; ls2[w] = s2; }
    __syncthreads();
    s  = ls[0] + ls[1] + ls[2] + ls[3];
    s2 = ls2[0] + ls2[1] + ls2[2] + ls2[3];
    const float mean = s * (1.f / D_);
    const float var  = s2 * (1.f / D_) - mean * mean;
    const float rstd = rsqrtf(var + 1e-5f);

    float4 o0 = {(v[0] - mean) * rstd, (v[1] - mean) * rstd,
                 (v[2] - mean) * rstd, (v[3] - mean) * rstd};
    float4 o1 = {(v[4] - mean) * rstd, (v[5] - mean) * rstd,
                 (v[6] - mean) * rstd, (v[7] - mean) * rstd};
    *(float4*)(outf + base + t * 8)     = o0;
    *(float4*)(outf + base + t * 8 + 4) = o1;
}

// ---------------------------------------------------------------------------
// Flash attention v12 (causal). KVBLK=32, fixed-C softmax, ones-MFMA denom,
// K/V LDS double-buffered one tile ahead, single raw s_barrier per tile,
// TWO m-tiles per wave (QBLK=32/wave, 128 q-rows/block). LDS 42 KiB.
// ---------------------------------------------------------------------------
__global__ __launch_bounds__(256, 2)
void attn_fwd12(const __bf16* __restrict__ Q, const __bf16* __restrict__ K,
                const __bf16* __restrict__ Vt, __bf16* __restrict__ O)
{
    __shared__ __align__(16) __bf16 Ks[2][32 * 128];   // 16 KiB, byte-swizzled
    __shared__ __align__(16) __bf16 Vs[2][128 * 32];   // 16 KiB, byte-swizzled
    __shared__ __align__(16) __bf16 Pl[4][32 * 40];    // 10 KiB, padded rows

    const float CMAX = 11.5f;   // score bound from qk-norm (Cauchy-Schwarz)

    const int tid  = threadIdx.x;
    const int lane = tid & 63;
    const int w    = tid >> 6;
    const int qt   = (int)gridDim.x - 1 - (int)blockIdx.x;  // heavy first
    const int h = blockIdx.y, b = blockIdx.z;
    const int q0w = qt * 128 + w * 32;
    const int fr = lane & 15, fq = lane >> 4;
    const size_t hb  = ((size_t)b * S_) * D_ + (size_t)h * DH_;   // Q,K,O [t][c]
    const size_t vtb = (((size_t)b * H_ + h) * DH_) * S_;          // Vt [dh][s]

    bf16x8 qf[2][4];
#pragma unroll
    for (int m = 0; m < 2; ++m)
#pragma unroll
        for (int ds = 0; ds < 4; ++ds)
            qf[m][ds] = *(const bf16x8*)(Q + hb + (size_t)(q0w + m * 16 + fr) * D_ + ds * 32 + fq * 8);

    f32x4 zero = {0.f, 0.f, 0.f, 0.f};
    f32x4 cacc[2][9];                   // [m][0..7] = ctx, [m][8] = denom
#pragma unroll
    for (int m = 0; m < 2; ++m)
#pragma unroll
        for (int dt = 0; dt < 9; ++dt) cacc[m][dt] = zero;

    bf16x8 ones8;
#pragma unroll
    for (int j = 0; j < 8; ++j) ones8[j] = (__bf16)1.0f;

    int krw[2], kco[2];
#pragma unroll
    for (int p = 0; p < 2; ++p) {
        const int c = p * 256 + tid;
        krw[p] = c >> 4;
        kco[p] = ((((c & 15) * 16) ^ ((krw[p] & 7) << 4)) >> 1);
    }
    int vdh[2], vco[2];
#pragma unroll
    for (int p = 0; p < 2; ++p) {
        const int c = p * 256 + tid;
        vdh[p] = c >> 2;
        vco[p] = (((c & 3) ^ ((vdh[p] ^ (vdh[p] >> 2)) & 3)) << 3);
    }

    int koff[4];
#pragma unroll
    for (int ds = 0; ds < 4; ++ds)
        koff[ds] = (((ds * 64 + fq * 16) ^ ((fr & 7) << 4)) >> 1);

    const int vrg = ((fq ^ ((fr ^ (fr >> 2)) & 3)) << 3);

    const int ntb = 4 * qt + 4;               // block tile count (32-key tiles)
    const int ntw = 4 * qt + w + 1;           // this wave's tiles (wave-uniform)

#define STAGE_KV(t, buf)                                                      \
    {                                                                         \
        const int _t = (t);                                                   \
        _Pragma("unroll")                                                     \
        for (int p = 0; p < 2; ++p)                                           \
            gll16(K + hb + (size_t)(_t * 32 + krw[p]) * D_ + kco[p],          \
                  &Ks[buf][(p * 256 + tid) * 8]);                             \
        _Pragma("unroll")                                                     \
        for (int p = 0; p < 2; ++p)                                           \
            gll16(Vt + vtb + (size_t)vdh[p] * S_ + _t * 32 + vco[p],          \
                  &Vs[buf][(p * 256 + tid) * 8]);                             \
    }

    STAGE_KV(0, 0);

    for (int kt = 0; kt < ntb; ++kt) {
        const int cur = kt & 1;
        asm volatile("s_waitcnt vmcnt(0)" ::: "memory");  // K/V[kt] landed
        __builtin_amdgcn_s_barrier();                     // tile kt-1 readers done
        asm volatile("" ::: "memory");

        if (kt + 1 < ntb) STAGE_KV(kt + 1, cur ^ 1);

        if (kt < ntw) {
            // ---- QK^T: 16 MFMA over 32 keys x 32 q (kfr shared by 2 m) ----
            f32x4 sacc[2][2];
#pragma unroll
            for (int m = 0; m < 2; ++m)
#pragma unroll
                for (int n = 0; n < 2; ++n) sacc[m][n] = zero;
#pragma unroll
            for (int n = 0; n < 2; ++n) {
                const __bf16* krow = &Ks[cur][(n * 16 + fr) * 128];
#pragma unroll
                for (int ds = 0; ds < 4; ++ds) {
                    bf16x8 kfr = *(const bf16x8*)(krow + koff[ds]);
                    sacc[0][n] = __builtin_amdgcn_mfma_f32_16x16x32_bf16(qf[0][ds], kfr, sacc[0][n], 0, 0, 0);
                    sacc[1][n] = __builtin_amdgcn_mfma_f32_16x16x32_bf16(qf[1][ds], kfr, sacc[1][n], 0, 0, 0);
                }
            }

            // ---- fixed-C softmax: p = exp(s - CMAX), mask post-exp ----
#pragma unroll
            for (int m = 0; m < 2; ++m)
#pragma unroll
                for (int r = 0; r < 4; ++r) {
                    const int qi = q0w + m * 16 + fq * 4 + r;
                    const int kb0 = kt * 32 + fr;
                    const float p0 = (kb0      <= qi) ? __expf(sacc[m][0][r] - CMAX) : 0.f;
                    const float p1 = (kb0 + 16 <= qi) ? __expf(sacc[m][1][r] - CMAX) : 0.f;
                    __bf16* pr = &Pl[w][(m * 16 + fq * 4 + r) * 40];
                    pr[fr]      = (__bf16)p0;
                    pr[16 + fr] = (__bf16)p1;
                }

            // ---- PV: 16 MFMA + 2 denom MFMA (vf shared by 2 m) ----
            bf16x8 pf0 = *(const bf16x8*)&Pl[w][(fr) * 40 + fq * 8];
            bf16x8 pf1 = *(const bf16x8*)&Pl[w][(16 + fr) * 40 + fq * 8];
            const __bf16* vbase = &Vs[cur][0];
#pragma unroll
            for (int dt = 0; dt < 8; ++dt) {
                bf16x8 vf = *(const bf16x8*)&vbase[(dt * 16 + fr) * 32 + vrg];
                cacc[0][dt] = __builtin_amdgcn_mfma_f32_16x16x32_bf16(pf0, vf, cacc[0][dt], 0, 0, 0);
                cacc[1][dt] = __builtin_amdgcn_mfma_f32_16x16x32_bf16(pf1, vf, cacc[1][dt], 0, 0, 0);
            }
            cacc[0][8] = __builtin_amdgcn_mfma_f32_16x16x32_bf16(pf0, ones8, cacc[0][8], 0, 0, 0);
            cacc[1][8] = __builtin_amdgcn_mfma_f32_16x16x32_bf16(pf1, ones8, cacc[1][8], 0, 0, 0);
        }
    }
#undef STAGE_KV

    // epilogue: normalize by MFMA-computed denominator + store
#pragma unroll
    for (int m = 0; m < 2; ++m)
#pragma unroll
        for (int dt = 0; dt < 8; ++dt)
#pragma unroll
            for (int r = 0; r < 4; ++r) {
                const int qi = q0w + m * 16 + fq * 4 + r;
                O[hb + (size_t)qi * D_ + dt * 16 + fr] = (__bf16)(cacc[m][dt][r] / cacc[m][8][r]);
            }
}

// ---------------------------------------------------------------------------
// launch — total workspace use: exactly 256 MiB
// ---------------------------------------------------------------------------
extern "C" void kernel_launch(void* const* d_in, const int* in_sizes, int n_in,
                              void* d_out, int out_size, void* d_ws, size_t ws_size,
                              hipStream_t stream)
{
    const float* x  = (const float*)d_in[0];
    const float* Wq = (const float*)d_in[2];  const float* bq = (const float*)d_in[3];
    const float* Wk = (const float*)d_in[4];  const float* bk = (const float*)d_in[5];
    const float* Wv = (const float*)d_in[6];  const float* bv = (const float*)d_in[7];
    const float* Wo = (const float*)d_in[8];  const float* bo = (const float*)d_in[9];
    const float* W1 = (const float*)d_in[10]; const float* b1 = (const float*)d_in[11];
    const float* W2 = (const float*)d_in[12]; const float* b2 = (const float*)d_in[13];
    float* out = (float*)d_out;

    const size_t NT  = (size_t)B_ * S_;            // 8192 rows
    const size_t MB  = 1024 * 1024;
    const size_t NEED = 256 * MB;
    if (ws_size < NEED) return;

    uint8_t* ws = (uint8_t*)d_ws;
    __bf16* Wb   = (__bf16*)(ws);              // 32 MiB: weights (wq|wk|wv|wo, later w1/w2)
    __bf16* xb   = (__bf16*)(ws + 32  * MB);   // 32 MiB: x bf16; later x1b
    __bf16* vtt  = (__bf16*)(ws + 64  * MB);   // 32 MiB: V transposed [b][h][dh][s]
    __bf16* fb   = (__bf16*)(ws + 96  * MB);   // 32 MiB: attn_out bf16; later f2 bf16
    __bf16* h1   = (__bf16*)(ws + 128 * MB);   // 128 MiB: FF hidden; hosts K/Q/ctx early
    __bf16* kb   = h1;
    __bf16* qb   = h1 + 16 * MB;
    __bf16* ctxb = h1 + 32 * MB;
    __bf16* x1b  = xb;

    const int WSZ = D_ * D_;                   // 4M elems per small weight
    __bf16* wqb = Wb;
    __bf16* wkb = Wb + (size_t)WSZ;
    __bf16* wvb = Wb + (size_t)2 * WSZ;
    __bf16* wob = Wb + (size_t)3 * WSZ;

    const dim3 blk2(512);
    const dim3 gD(D_ / 256, NT / 256);     // (8, 32)   = 256 blocks
    const dim3 gF(FF_ / 256, NT / 256);    // (32, 32)  = 1024 blocks

    // conversions: x and all four DxD weights (single dispatch each)
    f2b_kernel<<<2048, 256, 0, stream>>>(x, xb, (int)(NT * D_));
    f2b4_kernel<<<2048, 256, 0, stream>>>(Wq, Wk, Wv, Wo, Wb);

    // QKV projections
    gemm8p<0><<<gD, blk2, 0, stream>>>(xb, wqb, bq, qb, (int)NT, D_, D_);
    gemm8p<0><<<gD, blk2, 0, stream>>>(xb, wkb, bk, kb, (int)NT, D_, D_);
    gemm8p<2><<<gD, blk2, 0, stream>>>(xb, wvb, bv, vtt, (int)NT, D_, D_);

    // fused qk-norm (Q scaled by 1/sqrt(DH))
    const int halfB = (int)(NT * H_ / 4);
    qk_norm2<<<2 * halfB, 256, 0, stream>>>(qb, kb, halfB);

    attn_fwd12<<<dim3(S_ / 128, H_, B_), 256, 0, stream>>>(qb, kb, vtt, ctxb);

    gemm8p<0><<<gD, blk2, 0, stream>>>(ctxb, wob, bo, fb, (int)NT, D_, D_);
    add_ln_x<<<(int)NT, 256, 0, stream>>>(x, fb, x1b);

    // FFN (Wb reused for W1 then W2 — safe: Wo GEMM drained in stream order)
    f2b_kernel<<<2048, 256, 0, stream>>>(W1, Wb, FF_ * D_);
    gemm8p<1><<<gF, blk2, 0, stream>>>(x1b, Wb, b1, h1, (int)NT, FF_, D_);
    f2b_kernel<<<2048, 256, 0, stream>>>(W2, Wb, D_ * FF_);
    gemm8p<0><<<gD, blk2, 0, stream>>>(h1, Wb, b2, fb, (int)NT, D_, FF_);

    add_ln_f<<<(int)NT, 256, 0, stream>>>(x1b, fb, out);
}

// Round 18
// 1027.617 us; speedup vs baseline: 1.0332x; 1.0013x over previous
//
#include <hip/hip_runtime.h>
#include <hip/hip_bf16.h>
#include <stdint.h>

// Problem constants
#define B_  4
#define S_  2048
#define D_  2048
#define H_  16
#define DH_ 128
#define FF_ 8192

typedef __bf16 bf16x8 __attribute__((ext_vector_type(8)));
typedef __bf16 bf16x4 __attribute__((ext_vector_type(4)));
typedef __bf16 bf16x2 __attribute__((ext_vector_type(2)));
typedef float  f32x4  __attribute__((ext_vector_type(4)));

__device__ __forceinline__ void gll16(const void* g, void* l) {
    __builtin_amdgcn_global_load_lds(
        (const __attribute__((address_space(1))) void*)(g),
        (__attribute__((address_space(3))) void*)(l), 16, 0, 0);
}

// ---------------------------------------------------------------------------
// fp32 -> bf16 elementwise conversion
// ---------------------------------------------------------------------------
__global__ void f2b_kernel(const float* __restrict__ in, __bf16* __restrict__ out, int n)
{
    int i = blockIdx.x * blockDim.x + threadIdx.x;
    int stride = gridDim.x * blockDim.x;
    for (int j = i; j * 4 < n; j += stride) {
        float4 v = *(const float4*)(in + (size_t)j * 4);
        bf16x4 o = {(__bf16)v.x, (__bf16)v.y, (__bf16)v.z, (__bf16)v.w};
        *(bf16x4*)(out + (size_t)j * 4) = o;
    }
}

// ---------------------------------------------------------------------------
// f2b5: convert x (B*S*D) and four DxD fp32 weights in ONE dispatch.
// Weights land contiguously in wb (wq|wk|wv|wo).
// ---------------------------------------------------------------------------
__global__ void f2b5_kernel(const float* __restrict__ x,
                            const float* __restrict__ w0, const float* __restrict__ w1,
                            const float* __restrict__ w2, const float* __restrict__ w3,
                            __bf16* __restrict__ xb, __bf16* __restrict__ wb)
{
    const int x4 = (B_ * S_ * D_) >> 2;         // float4s in x
    const int w4 = (D_ * D_) >> 2;              // float4s per weight
    const int tot = x4 + 4 * w4;
    int i = blockIdx.x * blockDim.x + threadIdx.x;
    int stride = gridDim.x * blockDim.x;
    for (int j = i; j < tot; j += stride) {
        const float* src; __bf16* dst; int loc;
        if (j < x4) { src = x; dst = xb; loc = j; }
        else {
            const int jj = j - x4;
            const int ws = jj / w4;
            loc = jj - ws * w4;
            src = (ws == 0) ? w0 : (ws == 1) ? w1 : (ws == 2) ? w2 : w3;
            dst = wb + (size_t)ws * (D_ * D_);
        }
        float4 v = *(const float4*)(src + (size_t)loc * 4);
        bf16x4 o = {(__bf16)v.x, (__bf16)v.y, (__bf16)v.z, (__bf16)v.w};
        *(bf16x4*)(dst + (size_t)loc * 4) = o;
    }
}

// ---------------------------------------------------------------------------
// GEMM v4 (best known): 8-phase deep-pipelined 256x256, BK=64, 512 thr
// (8 waves 2Mx4N). LDS 128 KiB A/B x 2 bufs, full-spread XOR swizzle.
// Counted vmcnt only (6 @P3, 8 @P7); drains only on last iteration.
// EPI: 0 = bias ; 1 = bias+relu ; 2 = bias, write transposed Vt[b][h][dh][s]
// ---------------------------------------------------------------------------
#define GEMM_BODY                                                             \
    __shared__ __align__(16) __bf16 S[65536];                                 \
    const int tid  = threadIdx.x;                                             \
    const int lane = tid & 63;                                                \
    const int wid  = tid >> 6;                                                \
    const int wr   = wid >> 2;                                                \
    const int wc   = wid & 3;                                                 \
    const int fr   = lane & 15;                                               \
    const int fq   = lane >> 4;                                               \
    const int gx  = gridDim.x;                                                \
    const int nwg = gx * gridDim.y;                                           \
    int bid = blockIdx.y * gx + blockIdx.x;                                   \
    bid = (bid & 7) * (nwg >> 3) + (bid >> 3);                                \
    const int m0 = (bid / gx) << 8;                                           \
    const int n0 = (bid % gx) << 8;                                           \
    f32x4 zero = {0.f, 0.f, 0.f, 0.f};                                        \
    f32x4 acc[8][4];                                                          \
    _Pragma("unroll")                                                         \
    for (int m = 0; m < 8; ++m)                                               \
        _Pragma("unroll")                                                     \
        for (int n = 0; n < 4; ++n) acc[m][n] = zero;                         \
    const int srow8 = tid >> 3;                                               \
    const int sxo   = (((tid & 7) ^ (srow8 & 7)) << 3);                       \
    const size_t Ksz = (size_t)K;                                             \
    const __bf16* gA = A  + (size_t)m0 * Ksz;                                 \
    const __bf16* gB = Bw + (size_t)n0 * Ksz;                                 \
    const int acol0 = ((fq)     ^ (fr & 7)) << 3;                             \
    const int acol1 = ((4 + fq) ^ (fr & 7)) << 3;                             \
    const int NT = K >> 6;                                                    \
    const int NI = NT >> 1;                                                   \
    _Pragma("unroll")                                                         \
    for (int q = 0; q < 4; ++q) { STQ(gA, 0, q, 0);     STQ(gB, 0, q, 32768); }\
    _Pragma("unroll")                                                         \
    for (int q = 0; q < 4; ++q) { STQ(gA, 1, q, 16384); STQ(gB, 1, q, 49152); }\
    asm volatile("s_waitcnt vmcnt(8)" ::: "memory");                          \
    BAR;                                                                      \
    for (int i = 0; i < NI; ++i) {                                            \
        const int t = 2 * i;                                                  \
        const bool g = (t + 2) < NT;                                          \
        bf16x8 af[4][2], bf[4][2];                                            \
        RDA(0, 0); RDB1(0, 0); RDB1(0, 1);                                    \
        MM(0, 0, 1);                                                          \
        RDB1(0, 2); RDB1(0, 3);                                               \
        BAR;                                                                  \
        if (g) { STQ(gA, t + 2, 0, 0); STQ(gA, t + 2, 2, 0); }                \
        MM(0, 2, 3);                                                          \
        RDA(0, 1);                                                            \
        BAR;                                                                  \
        if (g) { STQ(gB, t + 2, 0, 32768); STQ(gB, t + 2, 1, 32768); }        \
        MM(1, 0, 1);                                                          \
        BAR;                                                                  \
        if (g) { STQ(gB, t + 2, 2, 32768); STQ(gB, t + 2, 3, 32768); }        \
        MM(1, 2, 3);                                                          \
        if (g) asm volatile("s_waitcnt vmcnt(6)" ::: "memory");               \
        else   asm volatile("s_waitcnt vmcnt(0)" ::: "memory");               \
        BAR;                                                                  \
        RDA(1, 0); RDB1(1, 0); RDB1(1, 1);                                    \
        if (g) { STQ(gA, t + 2, 1, 0); STQ(gA, t + 2, 3, 0); }                \
        MM(0, 0, 1);                                                          \
        RDB1(1, 2); RDB1(1, 3);                                               \
        BAR;                                                                  \
        if (g) { STQ(gA, t + 3, 0, 16384); STQ(gA, t + 3, 2, 16384); }        \
        MM(0, 2, 3);                                                          \
        RDA(1, 1);                                                            \
        BAR;                                                                  \
        if (g) { STQ(gB, t + 3, 0, 49152); STQ(gB, t + 3, 1, 49152); }        \
        MM(1, 0, 1);                                                          \
        BAR;                                                                  \
        if (g) { STQ(gB, t + 3, 2, 49152); STQ(gB, t + 3, 3, 49152);          \
                 STQ(gA, t + 3, 1, 16384); STQ(gA, t + 3, 3, 16384); }        \
        MM(1, 2, 3);                                                          \
        if (g) asm volatile("s_waitcnt vmcnt(8)" ::: "memory");               \
        else   asm volatile("s_waitcnt vmcnt(0)" ::: "memory");               \
        BAR;                                                                  \
    }

#define STQ(gp, tt, q, lofs)                                                  \
    gll16((gp) + (size_t)((q) * 64 + srow8) * Ksz + (size_t)(tt) * 64 + sxo,  \
          &S[(lofs) + (q) * 4096 + tid * 8])

#define RDA(buf, mh)                                                          \
    _Pragma("unroll")                                                         \
    for (int mi = 0; mi < 4; ++mi) {                                          \
        af[mi][0] = *(const bf16x8*)&S[(buf) * 16384 +                        \
                        (wr * 128 + (mh) * 64 + mi * 16 + fr) * 64 + acol0];  \
        af[mi][1] = *(const bf16x8*)&S[(buf) * 16384 +                        \
                        (wr * 128 + (mh) * 64 + mi * 16 + fr) * 64 + acol1];  \
    }

#define RDB1(buf, n_)                                                         \
    bf[n_][0] = *(const bf16x8*)&S[32768 + (buf) * 16384 +                    \
                    (wc * 64 + (n_) * 16 + fr) * 64 + acol0];                 \
    bf[n_][1] = *(const bf16x8*)&S[32768 + (buf) * 16384 +                    \
                    (wc * 64 + (n_) * 16 + fr) * 64 + acol1];

#define MM(mh, na, nb)                                                        \
    __builtin_amdgcn_s_setprio(1);                                            \
    _Pragma("unroll")                                                         \
    for (int mi = 0; mi < 4; ++mi) {                                          \
        acc[(mh)*4+mi][na] = __builtin_amdgcn_mfma_f32_16x16x32_bf16(         \
            af[mi][0], bf[na][0], acc[(mh)*4+mi][na], 0, 0, 0);               \
        acc[(mh)*4+mi][na] = __builtin_amdgcn_mfma_f32_16x16x32_bf16(         \
            af[mi][1], bf[na][1], acc[(mh)*4+mi][na], 0, 0, 0);               \
        acc[(mh)*4+mi][nb] = __builtin_amdgcn_mfma_f32_16x16x32_bf16(         \
            af[mi][0], bf[nb][0], acc[(mh)*4+mi][nb], 0, 0, 0);               \
        acc[(mh)*4+mi][nb] = __builtin_amdgcn_mfma_f32_16x16x32_bf16(         \
            af[mi][1], bf[nb][1], acc[(mh)*4+mi][nb], 0, 0, 0);               \
    }                                                                         \
    __builtin_amdgcn_s_setprio(0);

#define FENCE asm volatile("" ::: "memory")
#define BAR   FENCE; __builtin_amdgcn_s_barrier(); FENCE

template<int EPI>
__global__ __launch_bounds__(512, 1)
void gemm8p(const __bf16* __restrict__ A, const __bf16* __restrict__ Bw,
            const float* __restrict__ bias, __bf16* __restrict__ Cout,
            int M, int N, int K)
{
    GEMM_BODY

#pragma unroll
    for (int am = 0; am < 8; ++am) {
#pragma unroll
        for (int n = 0; n < 4; ++n) {
            const int col = n0 + wc * 64 + n * 16 + fr;
            const float bv = bias[col];
            if (EPI == 2) {
                const int row0 = m0 + wr * 128 + am * 16 + fq * 4;
                const int bi = row0 >> 11;
                const int si = row0 & (S_ - 1);
                bf16x4 o4;
#pragma unroll
                for (int r = 0; r < 4; ++r) o4[r] = (__bf16)(acc[am][n][r] + bv);
                *(bf16x4*)&Cout[(((size_t)bi * H_ + (col >> 7)) * DH_ + (col & (DH_ - 1))) * S_ + si] = o4;
            } else {
#pragma unroll
                for (int r = 0; r < 4; ++r) {
                    const int row = m0 + wr * 128 + am * 16 + fq * 4 + r;
                    float v = acc[am][n][r] + bv;
                    if (EPI == 1) v = fmaxf(v, 0.f);
                    Cout[(size_t)row * N + col] = (__bf16)v;
                }
            }
        }
    }
}

// ---------------------------------------------------------------------------
// gemmQKV: all three projections in one dispatch. B = wq|wk|wv contiguous
// ([6144][2048] row-major over K). Per-block (256-col aligned) epilogue
// select: Q/K -> row-major bf16 out; V -> transposed Vt[b][h][dh][s].
// ---------------------------------------------------------------------------
__global__ __launch_bounds__(512, 1)
void gemmQKV(const __bf16* __restrict__ A, const __bf16* __restrict__ Bw,
             const float* __restrict__ bq, const float* __restrict__ bk,
             const float* __restrict__ bv,
             __bf16* __restrict__ outQ, __bf16* __restrict__ outK,
             __bf16* __restrict__ outVt, int M, int N, int K)
{
    GEMM_BODY

    const bool isV = (n0 >= 2 * D_);
    const float* bias = (n0 < D_) ? bq : (n0 < 2 * D_) ? bk : bv;
    const int nbase   = (n0 < D_) ? 0  : (n0 < 2 * D_) ? D_ : 2 * D_;
    __bf16* outR = (n0 < D_) ? outQ : outK;

#pragma unroll
    for (int am = 0; am < 8; ++am) {
#pragma unroll
        for (int n = 0; n < 4; ++n) {
            const int col  = n0 + wc * 64 + n * 16 + fr;
            const int lcol = col - nbase;
            const float bvv = bias[lcol];
            if (isV) {
                const int row0 = m0 + wr * 128 + am * 16 + fq * 4;
                const int bi = row0 >> 11;
                const int si = row0 & (S_ - 1);
                bf16x4 o4;
#pragma unroll
                for (int r = 0; r < 4; ++r) o4[r] = (__bf16)(acc[am][n][r] + bvv);
                *(bf16x4*)&outVt[(((size_t)bi * H_ + (lcol >> 7)) * DH_ + (lcol & (DH_ - 1))) * S_ + si] = o4;
            } else {
#pragma unroll
                for (int r = 0; r < 4; ++r) {
                    const int row = m0 + wr * 128 + am * 16 + fq * 4 + r;
                    outR[(size_t)row * D_ + lcol] = (__bf16)(acc[am][n][r] + bvv);
                }
            }
        }
    }
}

#undef GEMM_BODY
#undef STQ
#undef RDA
#undef RDB1
#undef MM
#undef FENCE
#undef BAR

// ---------------------------------------------------------------------------
// Fused per-head LayerNorm over DH=128 for Q and K in one dispatch.
// ---------------------------------------------------------------------------
__global__ __launch_bounds__(256)
void qk_norm2(__bf16* __restrict__ qd, __bf16* __restrict__ kd, int halfBlocks)
{
    const bool isQ = (int)blockIdx.x < halfBlocks;
    __bf16* data = isQ ? qd : kd;
    const float scale = isQ ? 0.08838834764831845f : 1.0f;
    const int bid = isQ ? blockIdx.x : blockIdx.x - halfBlocks;
    const int row = bid * 4 + (threadIdx.x >> 6);
    const int t   = threadIdx.x & 63;
    const size_t base = (size_t)row * DH_;
    bf16x2 v2 = *(bf16x2*)(data + base + t * 2);
    const float a = (float)v2[0], b = (float)v2[1];
    float s  = a + b;
    float s2 = a * a + b * b;
#pragma unroll
    for (int o = 32; o; o >>= 1) { s += __shfl_xor(s, o); s2 += __shfl_xor(s2, o); }
    const float mean = s * (1.f / DH_);
    const float var  = s2 * (1.f / DH_) - mean * mean;
    const float rstd = rsqrtf(var + 1e-5f) * scale;
    bf16x2 o2 = {(__bf16)((a - mean) * rstd), (__bf16)((b - mean) * rstd)};
    *(bf16x2*)(data + base + t * 2) = o2;
}

// ---------------------------------------------------------------------------
// add_ln_x: x (fp32) + a (bf16) -> LN -> bf16 out.
// ---------------------------------------------------------------------------
__global__ __launch_bounds__(256)
void add_ln_x(const float* __restrict__ X, const __bf16* __restrict__ A2,
              __bf16* __restrict__ outb)
{
    __shared__ float ls[4], ls2[4];
    const int row = blockIdx.x;
    const int t   = threadIdx.x;
    const size_t base = (size_t)row * D_;

    float4 a = *(const float4*)(X + base + t * 8);
    float4 b = *(const float4*)(X + base + t * 8 + 4);
    bf16x8 c8 = *(const bf16x8*)(A2 + base + t * 8);
    float v[8] = {a.x + (float)c8[0], a.y + (float)c8[1], a.z + (float)c8[2], a.w + (float)c8[3],
                  b.x + (float)c8[4], b.y + (float)c8[5], b.z + (float)c8[6], b.w + (float)c8[7]};
    float s = 0.f, s2 = 0.f;
#pragma unroll
    for (int i = 0; i < 8; ++i) { s += v[i]; s2 += v[i] * v[i]; }
#pragma unroll
    for (int o = 32; o; o >>= 1) { s += __shfl_xor(s, o); s2 += __shfl_xor(s2, o); }
    const int w = t >> 6;
    if ((t & 63) == 0) { ls[w] = s; ls2[w] = s2; }
    __syncthreads();
    s  = ls[0] + ls[1] + ls[2] + ls[3];
    s2 = ls2[0] + ls2[1] + ls2[2] + ls2[3];
    const float mean = s * (1.f / D_);
    const float var  = s2 * (1.f / D_) - mean * mean;
    const float rstd = rsqrtf(var + 1e-5f);

    bf16x8 ob;
#pragma unroll
    for (int i = 0; i < 8; ++i) ob[i] = (__bf16)((v[i] - mean) * rstd);
    *(bf16x8*)(outb + base + t * 8) = ob;
}

// ---------------------------------------------------------------------------
// add_ln_f: x1 (bf16) + f2 (bf16) -> LN -> fp32 out.
// ---------------------------------------------------------------------------
__global__ __launch_bounds__(256)
void add_ln_f(const __bf16* __restrict__ X, const __bf16* __restrict__ A2,
              float* __restrict__ outf)
{
    __shared__ float ls[4], ls2[4];
    const int row = blockIdx.x;
    const int t   = threadIdx.x;
    const size_t base = (size_t)row * D_;

    bf16x8 a8 = *(const bf16x8*)(X  + base + t * 8);
    bf16x8 c8 = *(const bf16x8*)(A2 + base + t * 8);
    float v[8];
#pragma unroll
    for (int i = 0; i < 8; ++i) v[i] = (float)a8[i] + (float)c8[i];
    float s = 0.f, s2 = 0.f;
#pragma unroll
    for (int i = 0; i < 8; ++i) { s += v[i]; s2 += v[i] * v[i]; }
#pragma unroll
    for (int o = 32; o; o >>= 1) { s += __shfl_xor(s, o); s2 += __shfl_xor(s2, o); }
    const int w = t >> 6;
    if ((t & 63) == 0) { ls[w] = s; ls2[w] = s2; }
    __syncthreads();
    s  = ls[0] + ls[1] + ls[2] + ls[3];
    s2 = ls2[0] + ls2[1] + ls2[2] + ls2[3];
    const float mean = s * (1.f / D_);
    const float var  = s2 * (1.f / D_) - mean * mean;
    const float rstd = rsqrtf(var + 1e-5f);

    float4 o0 = {(v[0] - mean) * rstd, (v[1] - mean) * rstd,
                 (v[2] - mean) * rstd, (v[3] - mean) * rstd};
    float4 o1 = {(v[4] - mean) * rstd, (v[5] - mean) * rstd,
                 (v[6] - mean) * rstd, (v[7] - mean) * rstd};
    *(float4*)(outf + base + t * 8)     = o0;
    *(float4*)(outf + base + t * 8 + 4) = o1;
}

// ---------------------------------------------------------------------------
// Flash attention v12 (causal). KVBLK=32, fixed-C softmax, ones-MFMA denom,
// K/V LDS double-buffered one tile ahead, single raw s_barrier per tile,
// TWO m-tiles per wave (QBLK=32/wave, 128 q-rows/block). LDS 42 KiB.
// ---------------------------------------------------------------------------
__global__ __launch_bounds__(256, 2)
void attn_fwd12(const __bf16* __restrict__ Q, const __bf16* __restrict__ K,
                const __bf16* __restrict__ Vt, __bf16* __restrict__ O)
{
    __shared__ __align__(16) __bf16 Ks[2][32 * 128];   // 16 KiB, byte-swizzled
    __shared__ __align__(16) __bf16 Vs[2][128 * 32];   // 16 KiB, byte-swizzled
    __shared__ __align__(16) __bf16 Pl[4][32 * 40];    // 10 KiB, padded rows

    const float CMAX = 11.5f;   // score bound from qk-norm (Cauchy-Schwarz)

    const int tid  = threadIdx.x;
    const int lane = tid & 63;
    const int w    = tid >> 6;
    const int qt   = (int)gridDim.x - 1 - (int)blockIdx.x;  // heavy first
    const int h = blockIdx.y, b = blockIdx.z;
    const int q0w = qt * 128 + w * 32;
    const int fr = lane & 15, fq = lane >> 4;
    const size_t hb  = ((size_t)b * S_) * D_ + (size_t)h * DH_;   // Q,K,O [t][c]
    const size_t vtb = (((size_t)b * H_ + h) * DH_) * S_;          // Vt [dh][s]

    bf16x8 qf[2][4];
#pragma unroll
    for (int m = 0; m < 2; ++m)
#pragma unroll
        for (int ds = 0; ds < 4; ++ds)
            qf[m][ds] = *(const bf16x8*)(Q + hb + (size_t)(q0w + m * 16 + fr) * D_ + ds * 32 + fq * 8);

    f32x4 zero = {0.f, 0.f, 0.f, 0.f};
    f32x4 cacc[2][9];                   // [m][0..7] = ctx, [m][8] = denom
#pragma unroll
    for (int m = 0; m < 2; ++m)
#pragma unroll
        for (int dt = 0; dt < 9; ++dt) cacc[m][dt] = zero;

    bf16x8 ones8;
#pragma unroll
    for (int j = 0; j < 8; ++j) ones8[j] = (__bf16)1.0f;

    int krw[2], kco[2];
#pragma unroll
    for (int p = 0; p < 2; ++p) {
        const int c = p * 256 + tid;
        krw[p] = c >> 4;
        kco[p] = ((((c & 15) * 16) ^ ((krw[p] & 7) << 4)) >> 1);
    }
    int vdh[2], vco[2];
#pragma unroll
    for (int p = 0; p < 2; ++p) {
        const int c = p * 256 + tid;
        vdh[p] = c >> 2;
        vco[p] = (((c & 3) ^ ((vdh[p] ^ (vdh[p] >> 2)) & 3)) << 3);
    }

    int koff[4];
#pragma unroll
    for (int ds = 0; ds < 4; ++ds)
        koff[ds] = (((ds * 64 + fq * 16) ^ ((fr & 7) << 4)) >> 1);

    const int vrg = ((fq ^ ((fr ^ (fr >> 2)) & 3)) << 3);

    const int ntb = 4 * qt + 4;               // block tile count (32-key tiles)
    const int ntw = 4 * qt + w + 1;           // this wave's tiles (wave-uniform)

#define STAGE_KV(t, buf)                                                      \
    {                                                                         \
        const int _t = (t);                                                   \
        _Pragma("unroll")                                                     \
        for (int p = 0; p < 2; ++p)                                           \
            gll16(K + hb + (size_t)(_t * 32 + krw[p]) * D_ + kco[p],          \
                  &Ks[buf][(p * 256 + tid) * 8]);                             \
        _Pragma("unroll")                                                     \
        for (int p = 0; p < 2; ++p)                                           \
            gll16(Vt + vtb + (size_t)vdh[p] * S_ + _t * 32 + vco[p],          \
                  &Vs[buf][(p * 256 + tid) * 8]);                             \
    }

    STAGE_KV(0, 0);

    for (int kt = 0; kt < ntb; ++kt) {
        const int cur = kt & 1;
        asm volatile("s_waitcnt vmcnt(0)" ::: "memory");  // K/V[kt] landed
        __builtin_amdgcn_s_barrier();                     // tile kt-1 readers done
        asm volatile("" ::: "memory");

        if (kt + 1 < ntb) STAGE_KV(kt + 1, cur ^ 1);

        if (kt < ntw) {
            // ---- QK^T: 16 MFMA over 32 keys x 32 q (kfr shared by 2 m) ----
            f32x4 sacc[2][2];
#pragma unroll
            for (int m = 0; m < 2; ++m)
#pragma unroll
                for (int n = 0; n < 2; ++n) sacc[m][n] = zero;
#pragma unroll
            for (int n = 0; n < 2; ++n) {
                const __bf16* krow = &Ks[cur][(n * 16 + fr) * 128];
#pragma unroll
                for (int ds = 0; ds < 4; ++ds) {
                    bf16x8 kfr = *(const bf16x8*)(krow + koff[ds]);
                    sacc[0][n] = __builtin_amdgcn_mfma_f32_16x16x32_bf16(qf[0][ds], kfr, sacc[0][n], 0, 0, 0);
                    sacc[1][n] = __builtin_amdgcn_mfma_f32_16x16x32_bf16(qf[1][ds], kfr, sacc[1][n], 0, 0, 0);
                }
            }

            // ---- fixed-C softmax: p = exp(s - CMAX), mask post-exp ----
#pragma unroll
            for (int m = 0; m < 2; ++m)
#pragma unroll
                for (int r = 0; r < 4; ++r) {
                    const int qi = q0w + m * 16 + fq * 4 + r;
                    const int kb0 = kt * 32 + fr;
                    const float p0 = (kb0      <= qi) ? __expf(sacc[m][0][r] - CMAX) : 0.f;
                    const float p1 = (kb0 + 16 <= qi) ? __expf(sacc[m][1][r] - CMAX) : 0.f;
                    __bf16* pr = &Pl[w][(m * 16 + fq * 4 + r) * 40];
                    pr[fr]      = (__bf16)p0;
                    pr[16 + fr] = (__bf16)p1;
                }

            // ---- PV: 16 MFMA + 2 denom MFMA (vf shared by 2 m) ----
            bf16x8 pf0 = *(const bf16x8*)&Pl[w][(fr) * 40 + fq * 8];
            bf16x8 pf1 = *(const bf16x8*)&Pl[w][(16 + fr) * 40 + fq * 8];
            const __bf16* vbase = &Vs[cur][0];
#pragma unroll
            for (int dt = 0; dt < 8; ++dt) {
                bf16x8 vf = *(const bf16x8*)&vbase[(dt * 16 + fr) * 32 + vrg];
                cacc[0][dt] = __builtin_amdgcn_mfma_f32_16x16x32_bf16(pf0, vf, cacc[0][dt], 0, 0, 0);
                cacc[1][dt] = __builtin_amdgcn_mfma_f32_16x16x32_bf16(pf1, vf, cacc[1][dt], 0, 0, 0);
            }
            cacc[0][8] = __builtin_amdgcn_mfma_f32_16x16x32_bf16(pf0, ones8, cacc[0][8], 0, 0, 0);
            cacc[1][8] = __builtin_amdgcn_mfma_f32_16x16x32_bf16(pf1, ones8, cacc[1][8], 0, 0, 0);
        }
    }
#undef STAGE_KV

    // epilogue: normalize by MFMA-computed denominator + store
#pragma unroll
    for (int m = 0; m < 2; ++m)
#pragma unroll
        for (int dt = 0; dt < 8; ++dt)
#pragma unroll
            for (int r = 0; r < 4; ++r) {
                const int qi = q0w + m * 16 + fq * 4 + r;
                O[hb + (size_t)qi * D_ + dt * 16 + fr] = (__bf16)(cacc[m][dt][r] / cacc[m][8][r]);
            }
}

// ---------------------------------------------------------------------------
// launch — total workspace use: exactly 256 MiB
// ---------------------------------------------------------------------------
extern "C" void kernel_launch(void* const* d_in, const int* in_sizes, int n_in,
                              void* d_out, int out_size, void* d_ws, size_t ws_size,
                              hipStream_t stream)
{
    const float* x  = (const float*)d_in[0];
    const float* Wq = (const float*)d_in[2];  const float* bq = (const float*)d_in[3];
    const float* Wk = (const float*)d_in[4];  const float* bk = (const float*)d_in[5];
    const float* Wv = (const float*)d_in[6];  const float* bv = (const float*)d_in[7];
    const float* Wo = (const float*)d_in[8];  const float* bo = (const float*)d_in[9];
    const float* W1 = (const float*)d_in[10]; const float* b1 = (const float*)d_in[11];
    const float* W2 = (const float*)d_in[12]; const float* b2 = (const float*)d_in[13];
    float* out = (float*)d_out;

    const size_t NT  = (size_t)B_ * S_;            // 8192 rows
    const size_t MB  = 1024 * 1024;
    const size_t NEED = 256 * MB;
    if (ws_size < NEED) return;

    uint8_t* ws = (uint8_t*)d_ws;
    __bf16* Wb   = (__bf16*)(ws);              // 32 MiB: weights (wq|wk|wv|wo, later w1/w2)
    __bf16* xb   = (__bf16*)(ws + 32  * MB);   // 32 MiB: x bf16; later x1b
    __bf16* vtt  = (__bf16*)(ws + 64  * MB);   // 32 MiB: V transposed [b][h][dh][s]
    __bf16* fb   = (__bf16*)(ws + 96  * MB);   // 32 MiB: attn_out bf16; later f2 bf16
    __bf16* h1   = (__bf16*)(ws + 128 * MB);   // 128 MiB: FF hidden; hosts K/Q/ctx early
    __bf16* kb   = h1;
    __bf16* qb   = h1 + 16 * MB;
    __bf16* ctxb = h1 + 32 * MB;
    __bf16* x1b  = xb;

    const int WSZ = D_ * D_;
    __bf16* wob = Wb + (size_t)3 * WSZ;

    const dim3 blk2(512);
    const dim3 gD(D_ / 256, NT / 256);         // (8, 32)   = 256 blocks
    const dim3 gQKV(3 * D_ / 256, NT / 256);   // (24, 32)  = 768 blocks
    const dim3 gF(FF_ / 256, NT / 256);        // (32, 32)  = 1024 blocks

    // one conversion dispatch: x + wq|wk|wv|wo
    f2b5_kernel<<<4096, 256, 0, stream>>>(x, Wq, Wk, Wv, Wo, xb, Wb);

    // fused QKV projection (wq|wk|wv contiguous in Wb)
    gemmQKV<<<gQKV, blk2, 0, stream>>>(xb, Wb, bq, bk, bv, qb, kb, vtt,
                                       (int)NT, 3 * D_, D_);

    // fused qk-norm (Q scaled by 1/sqrt(DH))
    const int halfB = (int)(NT * H_ / 4);
    qk_norm2<<<2 * halfB, 256, 0, stream>>>(qb, kb, halfB);

    attn_fwd12<<<dim3(S_ / 128, H_, B_), 256, 0, stream>>>(qb, kb, vtt, ctxb);

    gemm8p<0><<<gD, blk2, 0, stream>>>(ctxb, wob, bo, fb, (int)NT, D_, D_);
    add_ln_x<<<(int)NT, 256, 0, stream>>>(x, fb, x1b);

    // FFN (Wb reused for W1 then W2 — safe: Wo GEMM drained in stream order)
    f2b_kernel<<<2048, 256, 0, stream>>>(W1, Wb, FF_ * D_);
    gemm8p<1><<<gF, blk2, 0, stream>>>(x1b, Wb, b1, h1, (int)NT, FF_, D_);
    f2b_kernel<<<2048, 256, 0, stream>>>(W2, Wb, D_ * FF_);
    gemm8p<0><<<gD, blk2, 0, stream>>>(h1, Wb, b2, fb, (int)NT, D_, FF_);

    add_ln_f<<<(int)NT, 256, 0, stream>>>(x1b, fb, out);
}